// Round 1
// baseline (908.749 us; speedup 1.0000x reference)
//
#include <hip/hip_runtime.h>

#define ROWS 2048
#define FLATK 33280
#define CHUNK_K 16640
#define SUBK 2080
#define NSTEP 65
#define S_DIM 520
#define SPLITP 16
#define OUT_THETA 40960
#define OUT_MU 303104
#define LOSCALE 2048.0f
#define INV_LOSCALE (1.0f/2048.0f)

typedef __attribute__((ext_vector_type(8))) _Float16 f16x8;
typedef __attribute__((ext_vector_type(8))) unsigned short u16x8;
typedef __attribute__((ext_vector_type(4))) float f32x4;

union H16 { _Float16 h; unsigned short u; };

static __device__ __forceinline__ void split16(float v, unsigned short& hi, unsigned short& lo) {
    H16 a, b;
    a.h = (_Float16)v;
    float r = (v - (float)a.h) * LOSCALE;
    b.h = (_Float16)r;
    hi = a.u; lo = b.u;
}

// async global->LDS, 16B per lane; lds base must be wave-uniform
static __device__ __forceinline__ void glds16(const unsigned short* g, unsigned short* l) {
    __builtin_amdgcn_global_load_lds((const __attribute__((address_space(1))) unsigned int*)g,
                                     (__attribute__((address_space(3))) unsigned int*)l,
                                     16, 0, 0);
}

// ---------------- K0: pl1_w fp32 -> f16 hi/lo planes ----------------
__global__ __launch_bounds__(256) void k_cvtB(const float4* __restrict__ in,
                                              ushort4* __restrict__ outh,
                                              ushort4* __restrict__ outl, int n4) {
    int i = blockIdx.x * 256 + threadIdx.x;
    if (i >= n4) return;
    float4 v = in[i];
    unsigned short h0, h1, h2, h3, l0, l1, l2, l3;
    split16(v.x, h0, l0); split16(v.y, h1, l1);
    split16(v.z, h2, l2); split16(v.w, h3, l3);
    outh[i] = make_ushort4(h0, h1, h2, h3);
    outl[i] = make_ushort4(l0, l1, l2, l3);
}

// ---------------- K1: fused conv1(VALU) + conv2(MFMA 16x16x32 f16 hi/lo 3-pass) ----------------
// grid dim3(2048, 2): block = one (b,l) row x position window (264 / 256 of 520).
// h1 = relu(conv1(x)) split to f16 hi/lo planes in LDS, transposed [pos][c] with
// XOR granule swizzle (g ^= pos&7) so MFMA b-frag ds_read_b128 is conflict-free.
// conv2 = w2 @ h1 via the same split-precision scheme as k_gemm (fp32-accurate).
// Output layout of Ah/Al identical to previous version; k_gemm unchanged.
__global__ __launch_bounds__(256) void k_conv(const float* __restrict__ x,
                                              const float* __restrict__ w1, const float* __restrict__ b1,
                                              const float* __restrict__ w2, const float* __restrict__ b2,
                                              unsigned short* __restrict__ Ah, unsigned short* __restrict__ Al,
                                              int z) {
    __shared__ __align__(16) unsigned short h1h[272 * 64];   // 34,816 B
    __shared__ __align__(16) unsigned short h1l[272 * 64];   // 34,816 B
    __shared__ __align__(16) float xs[8 * 272];              //  8,704 B
    __shared__ __align__(16) float w1s[512];                 //  2,048 B
    __shared__ float b1s[64];                                //    256 B  -> 80,640 B total, 2 blk/CU

    int t = threadIdx.x;
    int bl = blockIdx.x, by = blockIdx.y;
    int base = by * 264;
    int nloc = by ? 256 : 264;
    int ntile = by ? 16 : 17;
    int obase = z * 32;

    int lane = t & 63, w = t >> 6;
    int m = lane & 15, kg = lane >> 4;

    // preload w2 fragments (global; 16KB total, L2-hot across 4096 blocks) + b2 bias
    f16x8 wh[2][2], wl[2][2];
    float b2v[2][4];
#pragma unroll
    for (int ot = 0; ot < 2; ot++) {
#pragma unroll
        for (int ks = 0; ks < 2; ks++) {
            const float* wp = w2 + (size_t)(obase + ot * 16 + m) * 64 + ks * 32 + kg * 8;
            float4 va = *(const float4*)wp;
            float4 vb = *(const float4*)(wp + 4);
            float tmp[8] = {va.x, va.y, va.z, va.w, vb.x, vb.y, vb.z, vb.w};
            u16x8 ph, pl;
#pragma unroll
            for (int j = 0; j < 8; j++) {
                unsigned short a, b;
                split16(tmp[j], a, b);
                ph[j] = a; pl[j] = b;
            }
            wh[ot][ks] = *(f16x8*)&ph;
            wl[ot][ks] = *(f16x8*)&pl;
        }
#pragma unroll
        for (int r = 0; r < 4; r++) b2v[ot][r] = b2[obase + ot * 16 + kg * 4 + r];
    }

    // stage x window (zero-padded past S_DIM), w1, b1
    const float* xb = x + (size_t)bl * (8 * S_DIM);
#pragma unroll
    for (int ci = 0; ci < 8; ci++) {
        for (int lp = t; lp < 272; lp += 256) {
            int g = base + lp;
            xs[ci * 272 + lp] = (g < S_DIM) ? xb[ci * S_DIM + g] : 0.f;
        }
    }
    for (int i = t; i < 512; i += 256) w1s[i] = w1[i];
    if (t < 64) b1s[t] = b1[t];
    __syncthreads();

    // conv1 (VALU, fp32) -> relu -> split16 -> swizzled f16 hi/lo planes in LDS
    for (int lp = t; lp < 272; lp += 256) {
        float xv[8];
#pragma unroll
        for (int ci = 0; ci < 8; ci++) xv[ci] = xs[ci * 272 + lp];
        int sw = lp & 7;
#pragma unroll
        for (int cg = 0; cg < 8; cg++) {
            u16x8 ph, pl;
#pragma unroll
            for (int j = 0; j < 8; j++) {
                int c = cg * 8 + j;
                const float4 wa = *(const float4*)&w1s[c * 8];
                const float4 wb = *(const float4*)&w1s[c * 8 + 4];
                float a = b1s[c]
                    + wa.x * xv[0] + wa.y * xv[1] + wa.z * xv[2] + wa.w * xv[3]
                    + wb.x * xv[4] + wb.y * xv[5] + wb.z * xv[6] + wb.w * xv[7];
                a = fmaxf(a, 0.f);
                unsigned short hh, ll;
                split16(a, hh, ll);
                ph[j] = hh; pl[j] = ll;
            }
            int off = lp * 64 + ((cg ^ sw) << 3);
            *(u16x8*)&h1h[off] = ph;
            *(u16x8*)&h1l[off] = pl;
        }
    }
    __syncthreads();

    // conv2 via MFMA: out[o=32][pos] tiles of 16x16, K=64 (2 k-steps), 3 precision passes
    size_t Abase = (size_t)bl * CHUNK_K;
    for (int st = w; st < ntile; st += 4) {
        int lp0 = st * 16;
        int row = lp0 + m;
        f16x8 bh[2], bl2[2];
#pragma unroll
        for (int ks = 0; ks < 2; ks++) {
            int off = row * 64 + (((ks * 4 + kg) ^ (row & 7)) << 3);
            bh[ks]  = *(const f16x8*)&h1h[off];
            bl2[ks] = *(const f16x8*)&h1l[off];
        }
        bool ok = row < nloc;
        int pos = base + row;
#pragma unroll
        for (int ot = 0; ot < 2; ot++) {
            f32x4 ah = {0.f, 0.f, 0.f, 0.f}, am = {0.f, 0.f, 0.f, 0.f};
#pragma unroll
            for (int ks = 0; ks < 2; ks++) {
                ah = __builtin_amdgcn_mfma_f32_16x16x32_f16(wh[ot][ks], bh[ks],  ah, 0, 0, 0);
                am = __builtin_amdgcn_mfma_f32_16x16x32_f16(wl[ot][ks], bh[ks],  am, 0, 0, 0);
                am = __builtin_amdgcn_mfma_f32_16x16x32_f16(wh[ot][ks], bl2[ks], am, 0, 0, 0);
            }
            if (ok) {
#pragma unroll
                for (int r = 0; r < 4; r++) {
                    float v = fmaxf(b2v[ot][r] + ah[r] + am[r] * INV_LOSCALE, 0.f);
                    unsigned short hh, ll;
                    split16(v, hh, ll);
                    size_t o = (size_t)(ot * 16 + kg * 4 + r);
                    size_t off2 = Abase + o * S_DIM + pos;
                    Ah[off2] = hh;
                    Al[off2] = ll;
                }
            }
        }
    }
}

// ---------------- K2: MFMA GEMM, m97-style: global_load_lds + 128x128 tile ----------------
// grid dim3(16 rt, 2 ct, 8 sk), 256 thr. Wave-tile 64x64, fp16 hi/lo 3-pass.
__global__ __launch_bounds__(256) void k_gemm(const unsigned short* __restrict__ Ah,
                                              const unsigned short* __restrict__ Al,
                                              const unsigned short* __restrict__ Bh,
                                              const unsigned short* __restrict__ Bl,
                                              float* __restrict__ P, int z) {
    __shared__ __align__(16) unsigned short As_h[128 * 32];   // packed [row][k], 8 KB
    __shared__ __align__(16) unsigned short As_l[128 * 32];
    __shared__ __align__(16) unsigned short Bs_h[128 * 32];
    __shared__ __align__(16) unsigned short Bs_l[128 * 32];

    int t = threadIdx.x;
    int rt = blockIdx.x, ct = blockIdx.y, sk = blockIdx.z;
    int row0 = rt * 128, col0 = ct * 128;
    int kb0 = sk * SUBK;

    int w = t >> 6, lane = t & 63;

    // staging: wave w covers rows [w*16, w*16+16) and [64+w*16, ...), lane -> (row, 16B granule)
    int srow = w * 16 + (lane >> 2);
    int sg = (lane & 3) * 8;                    // ushort offset of granule
    const unsigned short* gAh0 = Ah + (size_t)(row0 + srow) * CHUNK_K + kb0 + sg;
    const unsigned short* gAl0 = Al + (size_t)(row0 + srow) * CHUNK_K + kb0 + sg;
    const unsigned short* gBh0 = Bh + (size_t)(col0 + srow) * FLATK + (size_t)z * CHUNK_K + kb0 + sg;
    const unsigned short* gBl0 = Bl + (size_t)(col0 + srow) * FLATK + (size_t)z * CHUNK_K + kb0 + sg;
    const size_t strideA64 = (size_t)64 * CHUNK_K;
    const size_t strideB64 = (size_t)64 * FLATK;
    unsigned short* lAh0 = &As_h[(w * 16) * 32];
    unsigned short* lAh1 = &As_h[(64 + w * 16) * 32];
    unsigned short* lAl0 = &As_l[(w * 16) * 32];
    unsigned short* lAl1 = &As_l[(64 + w * 16) * 32];
    unsigned short* lBh0 = &Bs_h[(w * 16) * 32];
    unsigned short* lBh1 = &Bs_h[(64 + w * 16) * 32];
    unsigned short* lBl0 = &Bs_l[(w * 16) * 32];
    unsigned short* lBl1 = &Bs_l[(64 + w * 16) * 32];

    int wr = (w >> 1) * 64, wc = (w & 1) * 64;
    int m = lane & 15, kg = lane >> 4;

    f32x4 acc_h[4][4], acc_m[4][4];
#pragma unroll
    for (int i = 0; i < 4; i++)
#pragma unroll
        for (int j = 0; j < 4; j++) {
            acc_h[i][j] = (f32x4){0.f, 0.f, 0.f, 0.f};
            acc_m[i][j] = (f32x4){0.f, 0.f, 0.f, 0.f};
        }

    for (int it = 0; it < NSTEP; ++it) {
        __syncthreads();   // previous iteration's LDS reads complete
        glds16(gAh0, lAh0);
        glds16(gAh0 + strideA64, lAh1);
        glds16(gAl0, lAl0);
        glds16(gAl0 + strideA64, lAl1);
        glds16(gBh0, lBh0);
        glds16(gBh0 + strideB64, lBh1);
        glds16(gBl0, lBl0);
        glds16(gBl0 + strideB64, lBl1);
        gAh0 += 32; gAl0 += 32; gBh0 += 32; gBl0 += 32;
        __syncthreads();   // drains vmcnt -> staged data visible

        f16x8 a_h[4], a_l[4], b_h[4], b_l[4];
#pragma unroll
        for (int i = 0; i < 4; i++) {
            int off = (wr + i * 16 + m) * 32 + kg * 8;
            a_h[i] = *reinterpret_cast<const f16x8*>(&As_h[off]);
            a_l[i] = *reinterpret_cast<const f16x8*>(&As_l[off]);
        }
#pragma unroll
        for (int j = 0; j < 4; j++) {
            int off = (wc + j * 16 + m) * 32 + kg * 8;
            b_h[j] = *reinterpret_cast<const f16x8*>(&Bs_h[off]);
            b_l[j] = *reinterpret_cast<const f16x8*>(&Bs_l[off]);
        }
#pragma unroll
        for (int i = 0; i < 4; i++)
#pragma unroll
            for (int j = 0; j < 4; j++) {
                acc_h[i][j] = __builtin_amdgcn_mfma_f32_16x16x32_f16(a_h[i], b_h[j], acc_h[i][j], 0, 0, 0);
                acc_m[i][j] = __builtin_amdgcn_mfma_f32_16x16x32_f16(a_l[i], b_h[j], acc_m[i][j], 0, 0, 0);
                acc_m[i][j] = __builtin_amdgcn_mfma_f32_16x16x32_f16(a_h[i], b_l[j], acc_m[i][j], 0, 0, 0);
            }
    }

    float* Pp = P + (size_t)(z * 8 + sk) * (ROWS * 256);
    int rbase = row0 + wr + (lane >> 4) * 4;
    int cbase = col0 + wc + (lane & 15);
#pragma unroll
    for (int i = 0; i < 4; i++)
#pragma unroll
        for (int j = 0; j < 4; j++)
#pragma unroll
            for (int r = 0; r < 4; r++) {
                int rr = rbase + i * 16 + r;
                int cc = cbase + j * 16;
                Pp[(size_t)rr * 256 + cc] = acc_h[i][j][r] + acc_m[i][j][r] * INV_LOSCALE;
            }
}

// ---------------- K3: reduce + bias + relu + pl2 + Theta ----------------
__global__ __launch_bounds__(128) void k_head(const float* __restrict__ P,
                                              const float* __restrict__ pl1b,
                                              const float* __restrict__ pl2w,
                                              const float* __restrict__ pl2b,
                                              float* __restrict__ out) {
    __shared__ __align__(16) float hs[256];
    __shared__ float Rls[128];
    int row = blockIdx.x;
    int t = threadIdx.x;
    for (int c = t; c < 256; c += 128) {
        float v = pl1b[c];
#pragma unroll
        for (int zz = 0; zz < SPLITP; zz++) v += P[(size_t)zz * (ROWS * 256) + (size_t)row * 256 + c];
        hs[c] = fmaxf(v, 0.f);
    }
    __syncthreads();
    {
        float v = pl2b[t];
        const float4* wr = reinterpret_cast<const float4*>(pl2w + (size_t)t * 256);
        const float4* hv = reinterpret_cast<const float4*>(hs);
#pragma unroll 8
        for (int c4 = 0; c4 < 64; c4++) {
            float4 wq = wr[c4], h = hv[c4];
            v += wq.x * h.x + wq.y * h.y + wq.z * h.z + wq.w * h.w;
        }
        Rls[t] = v;
    }
    __syncthreads();
    if (t < 64) {
        float pr = Rls[t], pi = Rls[64 + t];
        float nrm = fmaxf(sqrtf(pr * pr + pi * pi), 1e-12f);
        float* th = out + OUT_THETA + (size_t)row * 128 + t * 2;
        th[0] = pr / nrm;
        th[1] = pi / nrm;
    }
}

// ---------------- K4: einsums + MLPs + softmax + norm ----------------
__global__ __launch_bounds__(256) void k_tail(const float* __restrict__ Hre, const float* __restrict__ Him,
                                              const float* __restrict__ chre, const float* __restrict__ chim,
                                              const float* __restrict__ b1w, const float* __restrict__ b1b,
                                              const float* __restrict__ b2w, const float* __restrict__ b2b,
                                              const float* __restrict__ b3w, const float* __restrict__ b3b,
                                              const float* __restrict__ p1w, const float* __restrict__ p1b,
                                              const float* __restrict__ p2w, const float* __restrict__ p2b,
                                              float* __restrict__ out) {
    int b = blockIdx.x, t = threadIdx.x;
    __shared__ float trs[256], tis[256];
    __shared__ float red[512];
    __shared__ __align__(16) float cH[64];
    __shared__ __align__(16) float u1[128];
    __shared__ __align__(16) float u2[128];
    __shared__ __align__(16) float q1[128];
    __shared__ float wv[80];
    __shared__ float sc[4];

    const float* th = out + OUT_THETA + (size_t)b * 512;
    for (int i = t; i < 256; i += 256) { trs[i] = th[2 * i]; tis[i] = th[2 * i + 1]; }
    __syncthreads();

    {
        int part = t >> 5, km = t & 31, k = km >> 3, m = km & 7;
        const float* hr = Hre + (size_t)b * 8192 + m * 1024 + k;
        const float* hi = Him + (size_t)b * 8192 + m * 1024 + k;
        float a1 = 0.f, a2 = 0.f;
        for (int n = part * 8; n < part * 8 + 8; n++) {
#pragma unroll
            for (int l = 0; l < 4; l++) {
                float re = hr[n * 16 + l * 4], im = hi[n * 16 + l * 4];
                float tr = trs[l * 64 + n], ti = tis[l * 64 + n];
                a1 += re * tr + im * ti;
                a2 += re * ti - im * tr;
            }
        }
        red[(part * 32 + km) * 2 + 0] = a1;
        red[(part * 32 + km) * 2 + 1] = a2;
    }
    __syncthreads();
    if (t < 32) {
        float top = 0.f, bot = 0.f;
#pragma unroll
        for (int p = 0; p < 8; p++) { top += red[(p * 32 + t) * 2]; bot += red[(p * 32 + t) * 2 + 1]; }
        int k2 = t >> 3, m2 = t & 7;
        cH[k2 * 16 + m2]     = top + chre[b * 32 + t];
        cH[k2 * 16 + 8 + m2] = bot + chim[b * 32 + t];
    }
    __syncthreads();

    const float4* ch4 = reinterpret_cast<const float4*>(cH);
    if (t < 128) {
        float v = b1b[t];
        const float4* wq = reinterpret_cast<const float4*>(b1w + (size_t)t * 64);
#pragma unroll
        for (int j = 0; j < 16; j++) {
            float4 a = wq[j], c = ch4[j];
            v += a.x * c.x + a.y * c.y + a.z * c.z + a.w * c.w;
        }
        u1[t] = fmaxf(v, 0.f);
    } else {
        int o = t - 128;
        float v = p1b[o];
        const float4* wq = reinterpret_cast<const float4*>(p1w + (size_t)o * 64);
#pragma unroll
        for (int j = 0; j < 16; j++) {
            float4 a = wq[j], c = ch4[j];
            v += a.x * c.x + a.y * c.y + a.z * c.z + a.w * c.w;
        }
        q1[o] = fmaxf(v, 0.f);
    }
    __syncthreads();

    if (t < 128) {
        float v = b2b[t];
        const float4* wq = reinterpret_cast<const float4*>(b2w + (size_t)t * 128);
        const float4* uu = reinterpret_cast<const float4*>(u1);
#pragma unroll
        for (int j = 0; j < 32; j++) {
            float4 a = wq[j], c = uu[j];
            v += a.x * c.x + a.y * c.y + a.z * c.z + a.w * c.w;
        }
        u2[t] = fmaxf(v, 0.f);
    } else if (t < 130) {
        int o = t - 128;
        float v = p2b[o];
        const float4* wq = reinterpret_cast<const float4*>(p2w + (size_t)o * 128);
        const float4* qq = reinterpret_cast<const float4*>(q1);
#pragma unroll
        for (int j = 0; j < 32; j++) {
            float4 a = wq[j], c = qq[j];
            v += a.x * c.x + a.y * c.y + a.z * c.z + a.w * c.w;
        }
        sc[o] = v;
    }
    __syncthreads();

    if (t < 80) {
        float v = b3b[t];
        const float4* wq = reinterpret_cast<const float4*>(b3w + (size_t)t * 128);
        const float4* uu = reinterpret_cast<const float4*>(u2);
#pragma unroll
        for (int j = 0; j < 32; j++) {
            float4 a = wq[j], c = uu[j];
            v += a.x * c.x + a.y * c.y + a.z * c.z + a.w * c.w;
        }
        wv[t] = v;
    }
    __syncthreads();

    if (t == 0) {
        float mx = fmaxf(sc[0], sc[1]);
        float e0 = expf(sc[0] - mx), e1 = expf(sc[1] - mx);
        float s = e0 + e1;
        float mu0 = e0 / s, mu1 = e1 / s;
        out[OUT_MU + b * 2]     = mu0;
        out[OUT_MU + b * 2 + 1] = mu1;
        float ss = 0.f;
        for (int j = 0; j < 80; j++) ss += wv[j] * wv[j];
        float wn = fmaxf(sqrtf(ss), 1e-12f);
        sc[2] = 3.16227766017f * sqrtf(mu0) / wn;
    }
    __syncthreads();
    if (t < 80) out[b * 80 + t] = wv[t] * sc[2];
}

extern "C" void kernel_launch(void* const* d_in, const int* in_sizes, int n_in,
                              void* d_out, int out_size, void* d_ws, size_t ws_size,
                              hipStream_t stream) {
    const float* x    = (const float*)d_in[0];
    const float* Hre  = (const float*)d_in[1];
    const float* Him  = (const float*)d_in[2];
    const float* chre = (const float*)d_in[3];
    const float* chim = (const float*)d_in[4];
    const float* c1w  = (const float*)d_in[5];
    const float* c1b  = (const float*)d_in[6];
    const float* c2w  = (const float*)d_in[7];
    const float* c2b  = (const float*)d_in[8];
    const float* pl1w = (const float*)d_in[9];
    const float* pl1b = (const float*)d_in[10];
    const float* pl2w = (const float*)d_in[11];
    const float* pl2b = (const float*)d_in[12];
    const float* b1w  = (const float*)d_in[13];
    const float* b1b  = (const float*)d_in[14];
    const float* b2w  = (const float*)d_in[15];
    const float* b2b  = (const float*)d_in[16];
    const float* b3w  = (const float*)d_in[17];
    const float* b3b  = (const float*)d_in[18];
    const float* p1w  = (const float*)d_in[19];
    const float* p1b  = (const float*)d_in[20];
    const float* p2w  = (const float*)d_in[21];
    const float* p2b  = (const float*)d_in[22];
    float* out = (float*)d_out;

    char* ws = (char*)d_ws;
    unsigned short* Ah = (unsigned short*)(ws + 0);           //  68,157,440 B
    unsigned short* Al = (unsigned short*)(ws + 68157440u);   //  68,157,440 B
    float* P           = (float*)(ws + 136314880u);           //  33,554,432 B  (end 169,869,312)
    unsigned short* Bh = (unsigned short*)(ws + 169869312u);  //  17,039,360 B
    unsigned short* Bl = (unsigned short*)(ws + 186908672u);  //  17,039,360 B  (end 203,948,032; ws >= this, proven R7)

    k_cvtB<<<8320, 256, 0, stream>>>((const float4*)pl1w, (ushort4*)Bh, (ushort4*)Bl, 2129920);
    for (int z = 0; z < 2; z++) {
        k_conv<<<dim3(2048, 2), 256, 0, stream>>>(x, c1w, c1b, c2w, c2b, Ah, Al, z);
        k_gemm<<<dim3(16, 2, 8), 256, 0, stream>>>(Ah, Al, Bh, Bl, P, z);
    }
    k_head<<<2048, 128, 0, stream>>>(P, pl1b, pl2w, pl2b, out);
    k_tail<<<512, 256, 0, stream>>>(Hre, Him, chre, chim, b1w, b1b, b2w, b2b,
                                    b3w, b3b, p1w, p1b, p2w, p2b, out);
}

// Round 2
// 607.137 us; speedup vs baseline: 1.4968x; 1.4968x over previous
//
#include <hip/hip_runtime.h>

#define ROWS 2048
#define FLATK 33280
#define CHUNK_K 16640
#define SUBK 2080
#define NSTEP 65
#define S_DIM 520
#define SPLITP 16
#define OUT_THETA 40960
#define OUT_MU 303104
#define LOSCALE 2048.0f
#define INV_LOSCALE (1.0f/2048.0f)

typedef __attribute__((ext_vector_type(8))) _Float16 f16x8;
typedef __attribute__((ext_vector_type(8))) unsigned short u16x8;
typedef __attribute__((ext_vector_type(4))) float f32x4;

union H16 { _Float16 h; unsigned short u; };

static __device__ __forceinline__ void split16(float v, unsigned short& hi, unsigned short& lo) {
    H16 a, b;
    a.h = (_Float16)v;
    float r = (v - (float)a.h) * LOSCALE;
    b.h = (_Float16)r;
    hi = a.u; lo = b.u;
}

// async global->LDS, 16B per lane; lds base must be wave-uniform
static __device__ __forceinline__ void glds16(const unsigned short* g, unsigned short* l) {
    __builtin_amdgcn_global_load_lds((const __attribute__((address_space(1))) unsigned int*)g,
                                     (__attribute__((address_space(3))) unsigned int*)l,
                                     16, 0, 0);
}

// ---------------- K0: pl1_w fp32 -> f16 hi/lo planes ----------------
__global__ __launch_bounds__(256) void k_cvtB(const float4* __restrict__ in,
                                              ushort4* __restrict__ outh,
                                              ushort4* __restrict__ outl, int n4) {
    int i = blockIdx.x * 256 + threadIdx.x;
    if (i >= n4) return;
    float4 v = in[i];
    unsigned short h0, h1, h2, h3, l0, l1, l2, l3;
    split16(v.x, h0, l0); split16(v.y, h1, l1);
    split16(v.z, h2, l2); split16(v.w, h3, l3);
    outh[i] = make_ushort4(h0, h1, h2, h3);
    outl[i] = make_ushort4(l0, l1, l2, l3);
}

// ---------------- K1: conv1 (VALU) + conv2 (MFMA) ----------------
// grid (2048, 9), 256 thr. Block = one (b,l) row x 64-position window (R0 shape).
// conv1: wave w computes ch [16w,16w+16) for pos=lane -> f16 hi/lo planes in LDS,
// layout [pos][ch] with XOR granule swizzle (g ^= pos&7) -> conflict-free b128 ops.
// conv2: MFMA 16x16x32 f16, A = h1 (M=pos), B = w2 frags in regs (N=out), K=64.
// hi/lo 3-pass (same numerics as k_gemm). C/D: lane holds 4 consecutive pos for one
// out -> ushort4 stores. LDS 20.7 KB, small VGPR: fixes R1's occupancy collapse.
__global__ __launch_bounds__(256) void k_conv(const float* __restrict__ x,
                                              const float* __restrict__ w1, const float* __restrict__ b1,
                                              const float* __restrict__ w2, const float* __restrict__ b2,
                                              unsigned short* __restrict__ Ah, unsigned short* __restrict__ Al,
                                              int z) {
    __shared__ __align__(16) float xs[8 * 64];                //  2 KB
    __shared__ __align__(16) float w1s[512];                  //  2 KB
    __shared__ float b1s[64];                                 // 256 B
    __shared__ __align__(16) unsigned short h1h[64 * 64];     //  8 KB
    __shared__ __align__(16) unsigned short h1l[64 * 64];     //  8 KB

    int t = threadIdx.x;
    int bl = blockIdx.x, st = blockIdx.y;
    int pbase = st * 64;
    int obase = z * 32;
    int lane = t & 63, w = t >> 6;
    int m = lane & 15, kg = lane >> 4;

    // stage x window (zero-padded), w1, b1
    const float* xb = x + (size_t)bl * (8 * S_DIM);
    for (int i = t; i < 512; i += 256) {
        int ci = i >> 6, p = i & 63;
        int g = pbase + p;
        xs[i] = (g < S_DIM) ? xb[ci * S_DIM + g] : 0.f;
        w1s[i] = w1[i];
    }
    if (t < 64) b1s[t] = b1[t];

    // w2 B-fragments: lane holds w2[out = obase+ot*16+m][k = ks*32+kg*8+j] (contiguous)
    f16x8 wh[2][2], wl[2][2];
    float b2v[2];
#pragma unroll
    for (int ot = 0; ot < 2; ot++) {
        b2v[ot] = b2[obase + ot * 16 + m];
#pragma unroll
        for (int ks = 0; ks < 2; ks++) {
            const float* wp = w2 + (size_t)(obase + ot * 16 + m) * 64 + ks * 32 + kg * 8;
            float4 va = *(const float4*)wp;
            float4 vb = *(const float4*)(wp + 4);
            float tmp[8] = {va.x, va.y, va.z, va.w, vb.x, vb.y, vb.z, vb.w};
            u16x8 ph, pl;
#pragma unroll
            for (int j = 0; j < 8; j++) {
                unsigned short a, b;
                split16(tmp[j], a, b);
                ph[j] = a; pl[j] = b;
            }
            wh[ot][ks] = *(f16x8*)&ph;
            wl[ot][ks] = *(f16x8*)&pl;
        }
    }
    __syncthreads();

    // conv1: wave w -> channels [16w, 16w+16), pos = lane
    {
        int pos = lane;
        int cg0 = w * 16;
        float xv[8];
#pragma unroll
        for (int ci = 0; ci < 8; ci++) xv[ci] = xs[ci * 64 + pos];
#pragma unroll
        for (int half = 0; half < 2; half++) {
            u16x8 ph, pl;
#pragma unroll
            for (int j = 0; j < 8; j++) {
                int c = cg0 + half * 8 + j;
                const float4 wa = *(const float4*)&w1s[c * 8];
                const float4 wb = *(const float4*)&w1s[c * 8 + 4];
                float a = b1s[c]
                    + wa.x * xv[0] + wa.y * xv[1] + wa.z * xv[2] + wa.w * xv[3]
                    + wb.x * xv[4] + wb.y * xv[5] + wb.z * xv[6] + wb.w * xv[7];
                a = fmaxf(a, 0.f);
                unsigned short hh, ll;
                split16(a, hh, ll);
                ph[j] = hh; pl[j] = ll;
            }
            int g = (cg0 >> 3) + half;
            int off = pos * 64 + ((g ^ (pos & 7)) << 3);
            *(u16x8*)&h1h[off] = ph;
            *(u16x8*)&h1l[off] = pl;
        }
    }
    __syncthreads();

    // conv2 MFMA: wave w -> pos tile [w*16, w*16+16), all 32 outs
    int p0 = w * 16;
    int prow = p0 + m;
    f16x8 a_h[2], a_l[2];
#pragma unroll
    for (int ks = 0; ks < 2; ks++) {
        int g = ks * 4 + kg;
        int off = prow * 64 + ((g ^ (prow & 7)) << 3);
        a_h[ks] = *(const f16x8*)&h1h[off];
        a_l[ks] = *(const f16x8*)&h1l[off];
    }

    size_t Abase = (size_t)bl * CHUNK_K;
    int pos4 = pbase + p0 + kg * 4;          // 4 consecutive positions per lane
    bool ok = pos4 < (S_DIM - 3);
#pragma unroll
    for (int ot = 0; ot < 2; ot++) {
        f32x4 ah = {0.f, 0.f, 0.f, 0.f}, am = {0.f, 0.f, 0.f, 0.f};
#pragma unroll
        for (int ks = 0; ks < 2; ks++) {
            ah = __builtin_amdgcn_mfma_f32_16x16x32_f16(a_h[ks], wh[ot][ks], ah, 0, 0, 0);
            am = __builtin_amdgcn_mfma_f32_16x16x32_f16(a_l[ks], wh[ot][ks], am, 0, 0, 0);
            am = __builtin_amdgcn_mfma_f32_16x16x32_f16(a_h[ks], wl[ot][ks], am, 0, 0, 0);
        }
        if (ok) {
            unsigned short hh[4], ll[4];
#pragma unroll
            for (int r = 0; r < 4; r++) {
                float v = fmaxf(b2v[ot] + ah[r] + am[r] * INV_LOSCALE, 0.f);
                split16(v, hh[r], ll[r]);
            }
            size_t off2 = Abase + (size_t)(ot * 16 + m) * S_DIM + pos4;
            *reinterpret_cast<ushort4*>(&Ah[off2]) = make_ushort4(hh[0], hh[1], hh[2], hh[3]);
            *reinterpret_cast<ushort4*>(&Al[off2]) = make_ushort4(ll[0], ll[1], ll[2], ll[3]);
        }
    }
}

// ---------------- K2: MFMA GEMM, m97-style: global_load_lds + 128x128 tile ----------------
// grid dim3(16 rt, 2 ct, 8 sk), 256 thr. Wave-tile 64x64, fp16 hi/lo 3-pass.
__global__ __launch_bounds__(256) void k_gemm(const unsigned short* __restrict__ Ah,
                                              const unsigned short* __restrict__ Al,
                                              const unsigned short* __restrict__ Bh,
                                              const unsigned short* __restrict__ Bl,
                                              float* __restrict__ P, int z) {
    __shared__ __align__(16) unsigned short As_h[128 * 32];   // packed [row][k], 8 KB
    __shared__ __align__(16) unsigned short As_l[128 * 32];
    __shared__ __align__(16) unsigned short Bs_h[128 * 32];
    __shared__ __align__(16) unsigned short Bs_l[128 * 32];

    int t = threadIdx.x;
    int rt = blockIdx.x, ct = blockIdx.y, sk = blockIdx.z;
    int row0 = rt * 128, col0 = ct * 128;
    int kb0 = sk * SUBK;

    int w = t >> 6, lane = t & 63;

    // staging: wave w covers rows [w*16, w*16+16) and [64+w*16, ...), lane -> (row, 16B granule)
    int srow = w * 16 + (lane >> 2);
    int sg = (lane & 3) * 8;                    // ushort offset of granule
    const unsigned short* gAh0 = Ah + (size_t)(row0 + srow) * CHUNK_K + kb0 + sg;
    const unsigned short* gAl0 = Al + (size_t)(row0 + srow) * CHUNK_K + kb0 + sg;
    const unsigned short* gBh0 = Bh + (size_t)(col0 + srow) * FLATK + (size_t)z * CHUNK_K + kb0 + sg;
    const unsigned short* gBl0 = Bl + (size_t)(col0 + srow) * FLATK + (size_t)z * CHUNK_K + kb0 + sg;
    const size_t strideA64 = (size_t)64 * CHUNK_K;
    const size_t strideB64 = (size_t)64 * FLATK;
    unsigned short* lAh0 = &As_h[(w * 16) * 32];
    unsigned short* lAh1 = &As_h[(64 + w * 16) * 32];
    unsigned short* lAl0 = &As_l[(w * 16) * 32];
    unsigned short* lAl1 = &As_l[(64 + w * 16) * 32];
    unsigned short* lBh0 = &Bs_h[(w * 16) * 32];
    unsigned short* lBh1 = &Bs_h[(64 + w * 16) * 32];
    unsigned short* lBl0 = &Bs_l[(w * 16) * 32];
    unsigned short* lBl1 = &Bs_l[(64 + w * 16) * 32];

    int wr = (w >> 1) * 64, wc = (w & 1) * 64;
    int m = lane & 15, kg = lane >> 4;

    f32x4 acc_h[4][4], acc_m[4][4];
#pragma unroll
    for (int i = 0; i < 4; i++)
#pragma unroll
        for (int j = 0; j < 4; j++) {
            acc_h[i][j] = (f32x4){0.f, 0.f, 0.f, 0.f};
            acc_m[i][j] = (f32x4){0.f, 0.f, 0.f, 0.f};
        }

    for (int it = 0; it < NSTEP; ++it) {
        __syncthreads();   // previous iteration's LDS reads complete
        glds16(gAh0, lAh0);
        glds16(gAh0 + strideA64, lAh1);
        glds16(gAl0, lAl0);
        glds16(gAl0 + strideA64, lAl1);
        glds16(gBh0, lBh0);
        glds16(gBh0 + strideB64, lBh1);
        glds16(gBl0, lBl0);
        glds16(gBl0 + strideB64, lBl1);
        gAh0 += 32; gAl0 += 32; gBh0 += 32; gBl0 += 32;
        __syncthreads();   // drains vmcnt -> staged data visible

        f16x8 a_h[4], a_l[4], b_h[4], b_l[4];
#pragma unroll
        for (int i = 0; i < 4; i++) {
            int off = (wr + i * 16 + m) * 32 + kg * 8;
            a_h[i] = *reinterpret_cast<const f16x8*>(&As_h[off]);
            a_l[i] = *reinterpret_cast<const f16x8*>(&As_l[off]);
        }
#pragma unroll
        for (int j = 0; j < 4; j++) {
            int off = (wc + j * 16 + m) * 32 + kg * 8;
            b_h[j] = *reinterpret_cast<const f16x8*>(&Bs_h[off]);
            b_l[j] = *reinterpret_cast<const f16x8*>(&Bs_l[off]);
        }
#pragma unroll
        for (int i = 0; i < 4; i++)
#pragma unroll
            for (int j = 0; j < 4; j++) {
                acc_h[i][j] = __builtin_amdgcn_mfma_f32_16x16x32_f16(a_h[i], b_h[j], acc_h[i][j], 0, 0, 0);
                acc_m[i][j] = __builtin_amdgcn_mfma_f32_16x16x32_f16(a_l[i], b_h[j], acc_m[i][j], 0, 0, 0);
                acc_m[i][j] = __builtin_amdgcn_mfma_f32_16x16x32_f16(a_h[i], b_l[j], acc_m[i][j], 0, 0, 0);
            }
    }

    float* Pp = P + (size_t)(z * 8 + sk) * (ROWS * 256);
    int rbase = row0 + wr + (lane >> 4) * 4;
    int cbase = col0 + wc + (lane & 15);
#pragma unroll
    for (int i = 0; i < 4; i++)
#pragma unroll
        for (int j = 0; j < 4; j++)
#pragma unroll
            for (int r = 0; r < 4; r++) {
                int rr = rbase + i * 16 + r;
                int cc = cbase + j * 16;
                Pp[(size_t)rr * 256 + cc] = acc_h[i][j][r] + acc_m[i][j][r] * INV_LOSCALE;
            }
}

// ---------------- K3: reduce + bias + relu + pl2 + Theta ----------------
__global__ __launch_bounds__(128) void k_head(const float* __restrict__ P,
                                              const float* __restrict__ pl1b,
                                              const float* __restrict__ pl2w,
                                              const float* __restrict__ pl2b,
                                              float* __restrict__ out) {
    __shared__ __align__(16) float hs[256];
    __shared__ float Rls[128];
    int row = blockIdx.x;
    int t = threadIdx.x;
    for (int c = t; c < 256; c += 128) {
        float v = pl1b[c];
#pragma unroll
        for (int zz = 0; zz < SPLITP; zz++) v += P[(size_t)zz * (ROWS * 256) + (size_t)row * 256 + c];
        hs[c] = fmaxf(v, 0.f);
    }
    __syncthreads();
    {
        float v = pl2b[t];
        const float4* wr = reinterpret_cast<const float4*>(pl2w + (size_t)t * 256);
        const float4* hv = reinterpret_cast<const float4*>(hs);
#pragma unroll 8
        for (int c4 = 0; c4 < 64; c4++) {
            float4 wq = wr[c4], h = hv[c4];
            v += wq.x * h.x + wq.y * h.y + wq.z * h.z + wq.w * h.w;
        }
        Rls[t] = v;
    }
    __syncthreads();
    if (t < 64) {
        float pr = Rls[t], pi = Rls[64 + t];
        float nrm = fmaxf(sqrtf(pr * pr + pi * pi), 1e-12f);
        float* th = out + OUT_THETA + (size_t)row * 128 + t * 2;
        th[0] = pr / nrm;
        th[1] = pi / nrm;
    }
}

// ---------------- K4: einsums + MLPs + softmax + norm ----------------
__global__ __launch_bounds__(256) void k_tail(const float* __restrict__ Hre, const float* __restrict__ Him,
                                              const float* __restrict__ chre, const float* __restrict__ chim,
                                              const float* __restrict__ b1w, const float* __restrict__ b1b,
                                              const float* __restrict__ b2w, const float* __restrict__ b2b,
                                              const float* __restrict__ b3w, const float* __restrict__ b3b,
                                              const float* __restrict__ p1w, const float* __restrict__ p1b,
                                              const float* __restrict__ p2w, const float* __restrict__ p2b,
                                              float* __restrict__ out) {
    int b = blockIdx.x, t = threadIdx.x;
    __shared__ float trs[256], tis[256];
    __shared__ float red[512];
    __shared__ __align__(16) float cH[64];
    __shared__ __align__(16) float u1[128];
    __shared__ __align__(16) float u2[128];
    __shared__ __align__(16) float q1[128];
    __shared__ float wv[80];
    __shared__ float sc[4];

    const float* th = out + OUT_THETA + (size_t)b * 512;
    for (int i = t; i < 256; i += 256) { trs[i] = th[2 * i]; tis[i] = th[2 * i + 1]; }
    __syncthreads();

    {
        int part = t >> 5, km = t & 31, k = km >> 3, m = km & 7;
        const float* hr = Hre + (size_t)b * 8192 + m * 1024 + k;
        const float* hi = Him + (size_t)b * 8192 + m * 1024 + k;
        float a1 = 0.f, a2 = 0.f;
        for (int n = part * 8; n < part * 8 + 8; n++) {
#pragma unroll
            for (int l = 0; l < 4; l++) {
                float re = hr[n * 16 + l * 4], im = hi[n * 16 + l * 4];
                float tr = trs[l * 64 + n], ti = tis[l * 64 + n];
                a1 += re * tr + im * ti;
                a2 += re * ti - im * tr;
            }
        }
        red[(part * 32 + km) * 2 + 0] = a1;
        red[(part * 32 + km) * 2 + 1] = a2;
    }
    __syncthreads();
    if (t < 32) {
        float top = 0.f, bot = 0.f;
#pragma unroll
        for (int p = 0; p < 8; p++) { top += red[(p * 32 + t) * 2]; bot += red[(p * 32 + t) * 2 + 1]; }
        int k2 = t >> 3, m2 = t & 7;
        cH[k2 * 16 + m2]     = top + chre[b * 32 + t];
        cH[k2 * 16 + 8 + m2] = bot + chim[b * 32 + t];
    }
    __syncthreads();

    const float4* ch4 = reinterpret_cast<const float4*>(cH);
    if (t < 128) {
        float v = b1b[t];
        const float4* wq = reinterpret_cast<const float4*>(b1w + (size_t)t * 64);
#pragma unroll
        for (int j = 0; j < 16; j++) {
            float4 a = wq[j], c = ch4[j];
            v += a.x * c.x + a.y * c.y + a.z * c.z + a.w * c.w;
        }
        u1[t] = fmaxf(v, 0.f);
    } else {
        int o = t - 128;
        float v = p1b[o];
        const float4* wq = reinterpret_cast<const float4*>(p1w + (size_t)o * 64);
#pragma unroll
        for (int j = 0; j < 16; j++) {
            float4 a = wq[j], c = ch4[j];
            v += a.x * c.x + a.y * c.y + a.z * c.z + a.w * c.w;
        }
        q1[o] = fmaxf(v, 0.f);
    }
    __syncthreads();

    if (t < 128) {
        float v = b2b[t];
        const float4* wq = reinterpret_cast<const float4*>(b2w + (size_t)t * 128);
        const float4* uu = reinterpret_cast<const float4*>(u1);
#pragma unroll
        for (int j = 0; j < 32; j++) {
            float4 a = wq[j], c = uu[j];
            v += a.x * c.x + a.y * c.y + a.z * c.z + a.w * c.w;
        }
        u2[t] = fmaxf(v, 0.f);
    } else if (t < 130) {
        int o = t - 128;
        float v = p2b[o];
        const float4* wq = reinterpret_cast<const float4*>(p2w + (size_t)o * 128);
        const float4* qq = reinterpret_cast<const float4*>(q1);
#pragma unroll
        for (int j = 0; j < 32; j++) {
            float4 a = wq[j], c = qq[j];
            v += a.x * c.x + a.y * c.y + a.z * c.z + a.w * c.w;
        }
        sc[o] = v;
    }
    __syncthreads();

    if (t < 80) {
        float v = b3b[t];
        const float4* wq = reinterpret_cast<const float4*>(b3w + (size_t)t * 128);
        const float4* uu = reinterpret_cast<const float4*>(u2);
#pragma unroll
        for (int j = 0; j < 32; j++) {
            float4 a = wq[j], c = uu[j];
            v += a.x * c.x + a.y * c.y + a.z * c.z + a.w * c.w;
        }
        wv[t] = v;
    }
    __syncthreads();

    if (t == 0) {
        float mx = fmaxf(sc[0], sc[1]);
        float e0 = expf(sc[0] - mx), e1 = expf(sc[1] - mx);
        float s = e0 + e1;
        float mu0 = e0 / s, mu1 = e1 / s;
        out[OUT_MU + b * 2]     = mu0;
        out[OUT_MU + b * 2 + 1] = mu1;
        float ss = 0.f;
        for (int j = 0; j < 80; j++) ss += wv[j] * wv[j];
        float wn = fmaxf(sqrtf(ss), 1e-12f);
        sc[2] = 3.16227766017f * sqrtf(mu0) / wn;
    }
    __syncthreads();
    if (t < 80) out[b * 80 + t] = wv[t] * sc[2];
}

extern "C" void kernel_launch(void* const* d_in, const int* in_sizes, int n_in,
                              void* d_out, int out_size, void* d_ws, size_t ws_size,
                              hipStream_t stream) {
    const float* x    = (const float*)d_in[0];
    const float* Hre  = (const float*)d_in[1];
    const float* Him  = (const float*)d_in[2];
    const float* chre = (const float*)d_in[3];
    const float* chim = (const float*)d_in[4];
    const float* c1w  = (const float*)d_in[5];
    const float* c1b  = (const float*)d_in[6];
    const float* c2w  = (const float*)d_in[7];
    const float* c2b  = (const float*)d_in[8];
    const float* pl1w = (const float*)d_in[9];
    const float* pl1b = (const float*)d_in[10];
    const float* pl2w = (const float*)d_in[11];
    const float* pl2b = (const float*)d_in[12];
    const float* b1w  = (const float*)d_in[13];
    const float* b1b  = (const float*)d_in[14];
    const float* b2w  = (const float*)d_in[15];
    const float* b2b  = (const float*)d_in[16];
    const float* b3w  = (const float*)d_in[17];
    const float* b3b  = (const float*)d_in[18];
    const float* p1w  = (const float*)d_in[19];
    const float* p1b  = (const float*)d_in[20];
    const float* p2w  = (const float*)d_in[21];
    const float* p2b  = (const float*)d_in[22];
    float* out = (float*)d_out;

    char* ws = (char*)d_ws;
    unsigned short* Ah = (unsigned short*)(ws + 0);           //  68,157,440 B
    unsigned short* Al = (unsigned short*)(ws + 68157440u);   //  68,157,440 B
    float* P           = (float*)(ws + 136314880u);           //  33,554,432 B  (end 169,869,312)
    unsigned short* Bh = (unsigned short*)(ws + 169869312u);  //  17,039,360 B
    unsigned short* Bl = (unsigned short*)(ws + 186908672u);  //  17,039,360 B  (end 203,948,032; ws >= this, proven R7)

    k_cvtB<<<8320, 256, 0, stream>>>((const float4*)pl1w, (ushort4*)Bh, (ushort4*)Bl, 2129920);
    for (int z = 0; z < 2; z++) {
        k_conv<<<dim3(2048, 9), 256, 0, stream>>>(x, c1w, c1b, c2w, c2b, Ah, Al, z);
        k_gemm<<<dim3(16, 2, 8), 256, 0, stream>>>(Ah, Al, Bh, Bl, P, z);
    }
    k_head<<<2048, 128, 0, stream>>>(P, pl1b, pl2w, pl2b, out);
    k_tail<<<512, 256, 0, stream>>>(Hre, Him, chre, chim, b1w, b1b, b2w, b2b,
                                    b3w, b3b, p1w, p1b, p2w, p2b, out);
}

// Round 3
// 524.094 us; speedup vs baseline: 1.7339x; 1.1585x over previous
//
#include <hip/hip_runtime.h>

#define ROWS 2048
#define FLATK 33280
#define CHUNK_K 16640
#define SUBK 2080
#define NSTEP 65
#define S_DIM 520
#define SPLITP 16
#define OUT_THETA 40960
#define OUT_MU 303104
#define LOSCALE 2048.0f
#define INV_LOSCALE (1.0f/2048.0f)

typedef __attribute__((ext_vector_type(8))) _Float16 f16x8;
typedef __attribute__((ext_vector_type(8))) unsigned short u16x8;
typedef __attribute__((ext_vector_type(4))) float f32x4;

union H16 { _Float16 h; unsigned short u; };

static __device__ __forceinline__ void split16(float v, unsigned short& hi, unsigned short& lo) {
    H16 a, b;
    a.h = (_Float16)v;
    float r = (v - (float)a.h) * LOSCALE;
    b.h = (_Float16)r;
    hi = a.u; lo = b.u;
}

// async global->LDS, 16B per lane; lds base must be wave-uniform
static __device__ __forceinline__ void glds16(const unsigned short* g, unsigned short* l) {
    __builtin_amdgcn_global_load_lds((const __attribute__((address_space(1))) unsigned int*)g,
                                     (__attribute__((address_space(3))) unsigned int*)l,
                                     16, 0, 0);
}

// ---------------- K0: pl1_w fp32 -> f16 hi/lo planes ----------------
__global__ __launch_bounds__(256) void k_cvtB(const float4* __restrict__ in,
                                              ushort4* __restrict__ outh,
                                              ushort4* __restrict__ outl, int n4) {
    int i = blockIdx.x * 256 + threadIdx.x;
    if (i >= n4) return;
    float4 v = in[i];
    unsigned short h0, h1, h2, h3, l0, l1, l2, l3;
    split16(v.x, h0, l0); split16(v.y, h1, l1);
    split16(v.z, h2, l2); split16(v.w, h3, l3);
    outh[i] = make_ushort4(h0, h1, h2, h3);
    outl[i] = make_ushort4(l0, l1, l2, l3);
}

// ---------------- K0b: w2 fp32 -> pre-packed per-lane MFMA fragments hi/lo ----------------
// slot s in [0,512): z=s>>8, ot=(s>>7)&1, ks=(s>>6)&1, lane=s&63.
// Wq[s*8 + j]       = hi(w2[z*32+ot*16+(lane&15)][ks*32+(lane>>4)*8+j])
// Wq[4096 + s*8 +j] = lo(...)
// Removes 32 split16 chains + 8 float4 loads per k_conv thread (was redundant x18432 blocks).
__global__ __launch_bounds__(256) void k_cvtW(const float* __restrict__ w2,
                                              unsigned short* __restrict__ Wq) {
    int t = threadIdx.x;
    for (int s = t; s < 512; s += 256) {
        int z = s >> 8, rem = s & 255;
        int ot = rem >> 7, ks = (rem >> 6) & 1, lane = rem & 63;
        int m = lane & 15, kg = lane >> 4;
        const float* wp = w2 + (size_t)(z * 32 + ot * 16 + m) * 64 + ks * 32 + kg * 8;
#pragma unroll
        for (int j = 0; j < 8; j++) {
            unsigned short hh, ll;
            split16(wp[j], hh, ll);
            Wq[s * 8 + j] = hh;
            Wq[4096 + s * 8 + j] = ll;
        }
    }
}

// ---------------- K1: conv1 (VALU) + conv2 (MFMA) ----------------
// grid (2048, 9), 256 thr. Block = one (b,l) row x 64-position window.
// conv1: wave w computes ch [16w,16w+16) for pos=lane -> f16 hi/lo planes in LDS,
// layout [pos][ch] with XOR granule swizzle (g ^= pos&7) -> conflict-free b128 ops.
// conv2: MFMA 16x16x32 f16, A = h1 (M=pos), B = w2 frags loaded pre-packed from Wq.
// hi/lo 3-pass (same numerics as k_gemm). Output layout of Ah/Al unchanged.
__global__ __launch_bounds__(256) void k_conv(const float* __restrict__ x,
                                              const float* __restrict__ w1, const float* __restrict__ b1,
                                              const unsigned short* __restrict__ Wq,
                                              const float* __restrict__ b2,
                                              unsigned short* __restrict__ Ah, unsigned short* __restrict__ Al,
                                              int z) {
    __shared__ __align__(16) float xs[8 * 64];                //  2 KB
    __shared__ __align__(16) float w1s[512];                  //  2 KB
    __shared__ float b1s[64];                                 // 256 B
    __shared__ __align__(16) unsigned short h1h[64 * 64];     //  8 KB
    __shared__ __align__(16) unsigned short h1l[64 * 64];     //  8 KB

    int t = threadIdx.x;
    int bl = blockIdx.x, st = blockIdx.y;
    int pbase = st * 64;
    int obase = z * 32;
    int lane = t & 63, w = t >> 6;
    int m = lane & 15, kg = lane >> 4;

    // stage x window (zero-padded), w1, b1
    const float* xb = x + (size_t)bl * (8 * S_DIM);
    for (int i = t; i < 512; i += 256) {
        int ci = i >> 6, p = i & 63;
        int g = pbase + p;
        xs[i] = (g < S_DIM) ? xb[ci * S_DIM + g] : 0.f;
        w1s[i] = w1[i];
    }
    if (t < 64) b1s[t] = b1[t];

    // w2 B-fragments: pre-packed by k_cvtW; 8 coalesced 16B loads per thread
    f16x8 wh[2][2], wl[2][2];
    float b2v[2];
#pragma unroll
    for (int ot = 0; ot < 2; ot++) {
        b2v[ot] = b2[obase + ot * 16 + m];
#pragma unroll
        for (int ks = 0; ks < 2; ks++) {
            int slot = ((z * 2 + ot) * 2 + ks) * 64 + lane;
            wh[ot][ks] = *(const f16x8*)&Wq[slot * 8];
            wl[ot][ks] = *(const f16x8*)&Wq[4096 + slot * 8];
        }
    }
    __syncthreads();

    // conv1: wave w -> channels [16w, 16w+16), pos = lane
    {
        int pos = lane;
        int cg0 = w * 16;
        float xv[8];
#pragma unroll
        for (int ci = 0; ci < 8; ci++) xv[ci] = xs[ci * 64 + pos];
#pragma unroll
        for (int half = 0; half < 2; half++) {
            u16x8 ph, pl;
#pragma unroll
            for (int j = 0; j < 8; j++) {
                int c = cg0 + half * 8 + j;
                const float4 wa = *(const float4*)&w1s[c * 8];
                const float4 wb = *(const float4*)&w1s[c * 8 + 4];
                float a = b1s[c]
                    + wa.x * xv[0] + wa.y * xv[1] + wa.z * xv[2] + wa.w * xv[3]
                    + wb.x * xv[4] + wb.y * xv[5] + wb.z * xv[6] + wb.w * xv[7];
                a = fmaxf(a, 0.f);
                unsigned short hh, ll;
                split16(a, hh, ll);
                ph[j] = hh; pl[j] = ll;
            }
            int g = (cg0 >> 3) + half;
            int off = pos * 64 + ((g ^ (pos & 7)) << 3);
            *(u16x8*)&h1h[off] = ph;
            *(u16x8*)&h1l[off] = pl;
        }
    }
    __syncthreads();

    // conv2 MFMA: wave w -> pos tile [w*16, w*16+16), all 32 outs
    int p0 = w * 16;
    int prow = p0 + m;
    f16x8 a_h[2], a_l[2];
#pragma unroll
    for (int ks = 0; ks < 2; ks++) {
        int g = ks * 4 + kg;
        int off = prow * 64 + ((g ^ (prow & 7)) << 3);
        a_h[ks] = *(const f16x8*)&h1h[off];
        a_l[ks] = *(const f16x8*)&h1l[off];
    }

    size_t Abase = (size_t)bl * CHUNK_K;
    int pos4 = pbase + p0 + kg * 4;          // 4 consecutive positions per lane
    bool ok = pos4 < (S_DIM - 3);
#pragma unroll
    for (int ot = 0; ot < 2; ot++) {
        f32x4 ah = {0.f, 0.f, 0.f, 0.f}, am = {0.f, 0.f, 0.f, 0.f};
#pragma unroll
        for (int ks = 0; ks < 2; ks++) {
            ah = __builtin_amdgcn_mfma_f32_16x16x32_f16(a_h[ks], wh[ot][ks], ah, 0, 0, 0);
            am = __builtin_amdgcn_mfma_f32_16x16x32_f16(a_l[ks], wh[ot][ks], am, 0, 0, 0);
            am = __builtin_amdgcn_mfma_f32_16x16x32_f16(a_h[ks], wl[ot][ks], am, 0, 0, 0);
        }
        if (ok) {
            unsigned short hh[4], ll[4];
#pragma unroll
            for (int r = 0; r < 4; r++) {
                float v = fmaxf(b2v[ot] + ah[r] + am[r] * INV_LOSCALE, 0.f);
                split16(v, hh[r], ll[r]);
            }
            size_t off2 = Abase + (size_t)(ot * 16 + m) * S_DIM + pos4;
            *reinterpret_cast<ushort4*>(&Ah[off2]) = make_ushort4(hh[0], hh[1], hh[2], hh[3]);
            *reinterpret_cast<ushort4*>(&Al[off2]) = make_ushort4(ll[0], ll[1], ll[2], ll[3]);
        }
    }
}

// ---------------- K2: MFMA GEMM, 64x128 tile, 512 blocks = 2/CU ----------------
// grid dim3(32 rt, 2 ct, 8 sk), 256 thr. Wave-tile 64x32, fp16 hi/lo 3-pass.
// Same staging idiom / numerics as the proven 128x128 version; only decomposition
// changed so two blocks co-reside per CU and cover each other's barrier drains.
__global__ __launch_bounds__(256) void k_gemm(const unsigned short* __restrict__ Ah,
                                              const unsigned short* __restrict__ Al,
                                              const unsigned short* __restrict__ Bh,
                                              const unsigned short* __restrict__ Bl,
                                              float* __restrict__ P, int z) {
    __shared__ __align__(16) unsigned short As_h[64 * 32];    // 4 KB
    __shared__ __align__(16) unsigned short As_l[64 * 32];    // 4 KB
    __shared__ __align__(16) unsigned short Bs_h[128 * 32];   // 8 KB
    __shared__ __align__(16) unsigned short Bs_l[128 * 32];   // 8 KB

    int t = threadIdx.x;
    int rt = blockIdx.x, ct = blockIdx.y, sk = blockIdx.z;
    int row0 = rt * 64, col0 = ct * 128;
    int kb0 = sk * SUBK;

    int w = t >> 6, lane = t & 63;
    int srow = lane >> 2;                       // 0..15
    int sg = (lane & 3) * 8;                    // ushort offset of 16B granule

    // staging: wave w -> A rows [w*16,w*16+16), B rows [w*32,w*32+32) (2 chunks)
    const unsigned short* gAh0 = Ah + (size_t)(row0 + w * 16 + srow) * CHUNK_K + kb0 + sg;
    const unsigned short* gAl0 = Al + (size_t)(row0 + w * 16 + srow) * CHUNK_K + kb0 + sg;
    const unsigned short* gBh0 = Bh + (size_t)(col0 + w * 32 + srow) * FLATK + (size_t)z * CHUNK_K + kb0 + sg;
    const unsigned short* gBl0 = Bl + (size_t)(col0 + w * 32 + srow) * FLATK + (size_t)z * CHUNK_K + kb0 + sg;
    const size_t strideB16 = (size_t)16 * FLATK;
    unsigned short* lAh  = &As_h[(w * 16) * 32];
    unsigned short* lAl  = &As_l[(w * 16) * 32];
    unsigned short* lBh0 = &Bs_h[(w * 32) * 32];
    unsigned short* lBh1 = &Bs_h[(w * 32 + 16) * 32];
    unsigned short* lBl0 = &Bs_l[(w * 32) * 32];
    unsigned short* lBl1 = &Bs_l[(w * 32 + 16) * 32];

    int m = lane & 15, kg = lane >> 4;

    f32x4 acc_h[4][2], acc_m[4][2];
#pragma unroll
    for (int i = 0; i < 4; i++)
#pragma unroll
        for (int j = 0; j < 2; j++) {
            acc_h[i][j] = (f32x4){0.f, 0.f, 0.f, 0.f};
            acc_m[i][j] = (f32x4){0.f, 0.f, 0.f, 0.f};
        }

    for (int it = 0; it < NSTEP; ++it) {
        __syncthreads();   // previous iteration's LDS reads complete
        glds16(gAh0, lAh);
        glds16(gAl0, lAl);
        glds16(gBh0, lBh0);
        glds16(gBh0 + strideB16, lBh1);
        glds16(gBl0, lBl0);
        glds16(gBl0 + strideB16, lBl1);
        gAh0 += 32; gAl0 += 32; gBh0 += 32; gBl0 += 32;
        __syncthreads();   // drains vmcnt -> staged data visible

        f16x8 a_h[4], a_l[4], b_h[2], b_l[2];
#pragma unroll
        for (int i = 0; i < 4; i++) {
            int off = (i * 16 + m) * 32 + kg * 8;
            a_h[i] = *reinterpret_cast<const f16x8*>(&As_h[off]);
            a_l[i] = *reinterpret_cast<const f16x8*>(&As_l[off]);
        }
#pragma unroll
        for (int j = 0; j < 2; j++) {
            int off = (w * 32 + j * 16 + m) * 32 + kg * 8;
            b_h[j] = *reinterpret_cast<const f16x8*>(&Bs_h[off]);
            b_l[j] = *reinterpret_cast<const f16x8*>(&Bs_l[off]);
        }
#pragma unroll
        for (int i = 0; i < 4; i++)
#pragma unroll
            for (int j = 0; j < 2; j++) {
                acc_h[i][j] = __builtin_amdgcn_mfma_f32_16x16x32_f16(a_h[i], b_h[j], acc_h[i][j], 0, 0, 0);
                acc_m[i][j] = __builtin_amdgcn_mfma_f32_16x16x32_f16(a_l[i], b_h[j], acc_m[i][j], 0, 0, 0);
                acc_m[i][j] = __builtin_amdgcn_mfma_f32_16x16x32_f16(a_h[i], b_l[j], acc_m[i][j], 0, 0, 0);
            }
    }

    float* Pp = P + (size_t)(z * 8 + sk) * (ROWS * 256);
    int rbase = row0 + kg * 4;
    int cbase = col0 + w * 32 + m;
#pragma unroll
    for (int i = 0; i < 4; i++)
#pragma unroll
        for (int j = 0; j < 2; j++)
#pragma unroll
            for (int r = 0; r < 4; r++) {
                int rr = rbase + i * 16 + r;
                int cc = cbase + j * 16;
                Pp[(size_t)rr * 256 + cc] = acc_h[i][j][r] + acc_m[i][j][r] * INV_LOSCALE;
            }
}

// ---------------- K3: reduce + bias + relu + pl2 + Theta ----------------
__global__ __launch_bounds__(128) void k_head(const float* __restrict__ P,
                                              const float* __restrict__ pl1b,
                                              const float* __restrict__ pl2w,
                                              const float* __restrict__ pl2b,
                                              float* __restrict__ out) {
    __shared__ __align__(16) float hs[256];
    __shared__ float Rls[128];
    int row = blockIdx.x;
    int t = threadIdx.x;
    for (int c = t; c < 256; c += 128) {
        float v = pl1b[c];
#pragma unroll
        for (int zz = 0; zz < SPLITP; zz++) v += P[(size_t)zz * (ROWS * 256) + (size_t)row * 256 + c];
        hs[c] = fmaxf(v, 0.f);
    }
    __syncthreads();
    {
        float v = pl2b[t];
        const float4* wr = reinterpret_cast<const float4*>(pl2w + (size_t)t * 256);
        const float4* hv = reinterpret_cast<const float4*>(hs);
#pragma unroll 8
        for (int c4 = 0; c4 < 64; c4++) {
            float4 wq = wr[c4], h = hv[c4];
            v += wq.x * h.x + wq.y * h.y + wq.z * h.z + wq.w * h.w;
        }
        Rls[t] = v;
    }
    __syncthreads();
    if (t < 64) {
        float pr = Rls[t], pi = Rls[64 + t];
        float nrm = fmaxf(sqrtf(pr * pr + pi * pi), 1e-12f);
        float* th = out + OUT_THETA + (size_t)row * 128 + t * 2;
        th[0] = pr / nrm;
        th[1] = pi / nrm;
    }
}

// ---------------- K4: einsums + MLPs + softmax + norm ----------------
__global__ __launch_bounds__(256) void k_tail(const float* __restrict__ Hre, const float* __restrict__ Him,
                                              const float* __restrict__ chre, const float* __restrict__ chim,
                                              const float* __restrict__ b1w, const float* __restrict__ b1b,
                                              const float* __restrict__ b2w, const float* __restrict__ b2b,
                                              const float* __restrict__ b3w, const float* __restrict__ b3b,
                                              const float* __restrict__ p1w, const float* __restrict__ p1b,
                                              const float* __restrict__ p2w, const float* __restrict__ p2b,
                                              float* __restrict__ out) {
    int b = blockIdx.x, t = threadIdx.x;
    __shared__ float trs[256], tis[256];
    __shared__ float red[512];
    __shared__ __align__(16) float cH[64];
    __shared__ __align__(16) float u1[128];
    __shared__ __align__(16) float u2[128];
    __shared__ __align__(16) float q1[128];
    __shared__ float wv[80];
    __shared__ float sc[4];

    const float* th = out + OUT_THETA + (size_t)b * 512;
    for (int i = t; i < 256; i += 256) { trs[i] = th[2 * i]; tis[i] = th[2 * i + 1]; }
    __syncthreads();

    {
        int part = t >> 5, km = t & 31, k = km >> 3, m = km & 7;
        const float* hr = Hre + (size_t)b * 8192 + m * 1024 + k;
        const float* hi = Him + (size_t)b * 8192 + m * 1024 + k;
        float a1 = 0.f, a2 = 0.f;
        for (int n = part * 8; n < part * 8 + 8; n++) {
#pragma unroll
            for (int l = 0; l < 4; l++) {
                float re = hr[n * 16 + l * 4], im = hi[n * 16 + l * 4];
                float tr = trs[l * 64 + n], ti = tis[l * 64 + n];
                a1 += re * tr + im * ti;
                a2 += re * ti - im * tr;
            }
        }
        red[(part * 32 + km) * 2 + 0] = a1;
        red[(part * 32 + km) * 2 + 1] = a2;
    }
    __syncthreads();
    if (t < 32) {
        float top = 0.f, bot = 0.f;
#pragma unroll
        for (int p = 0; p < 8; p++) { top += red[(p * 32 + t) * 2]; bot += red[(p * 32 + t) * 2 + 1]; }
        int k2 = t >> 3, m2 = t & 7;
        cH[k2 * 16 + m2]     = top + chre[b * 32 + t];
        cH[k2 * 16 + 8 + m2] = bot + chim[b * 32 + t];
    }
    __syncthreads();

    const float4* ch4 = reinterpret_cast<const float4*>(cH);
    if (t < 128) {
        float v = b1b[t];
        const float4* wq = reinterpret_cast<const float4*>(b1w + (size_t)t * 64);
#pragma unroll
        for (int j = 0; j < 16; j++) {
            float4 a = wq[j], c = ch4[j];
            v += a.x * c.x + a.y * c.y + a.z * c.z + a.w * c.w;
        }
        u1[t] = fmaxf(v, 0.f);
    } else {
        int o = t - 128;
        float v = p1b[o];
        const float4* wq = reinterpret_cast<const float4*>(p1w + (size_t)o * 64);
#pragma unroll
        for (int j = 0; j < 16; j++) {
            float4 a = wq[j], c = ch4[j];
            v += a.x * c.x + a.y * c.y + a.z * c.z + a.w * c.w;
        }
        q1[o] = fmaxf(v, 0.f);
    }
    __syncthreads();

    if (t < 128) {
        float v = b2b[t];
        const float4* wq = reinterpret_cast<const float4*>(b2w + (size_t)t * 128);
        const float4* uu = reinterpret_cast<const float4*>(u1);
#pragma unroll
        for (int j = 0; j < 32; j++) {
            float4 a = wq[j], c = uu[j];
            v += a.x * c.x + a.y * c.y + a.z * c.z + a.w * c.w;
        }
        u2[t] = fmaxf(v, 0.f);
    } else if (t < 130) {
        int o = t - 128;
        float v = p2b[o];
        const float4* wq = reinterpret_cast<const float4*>(p2w + (size_t)o * 128);
        const float4* qq = reinterpret_cast<const float4*>(q1);
#pragma unroll
        for (int j = 0; j < 32; j++) {
            float4 a = wq[j], c = qq[j];
            v += a.x * c.x + a.y * c.y + a.z * c.z + a.w * c.w;
        }
        sc[o] = v;
    }
    __syncthreads();

    if (t < 80) {
        float v = b3b[t];
        const float4* wq = reinterpret_cast<const float4*>(b3w + (size_t)t * 128);
        const float4* uu = reinterpret_cast<const float4*>(u2);
#pragma unroll
        for (int j = 0; j < 32; j++) {
            float4 a = wq[j], c = uu[j];
            v += a.x * c.x + a.y * c.y + a.z * c.z + a.w * c.w;
        }
        wv[t] = v;
    }
    __syncthreads();

    if (t == 0) {
        float mx = fmaxf(sc[0], sc[1]);
        float e0 = expf(sc[0] - mx), e1 = expf(sc[1] - mx);
        float s = e0 + e1;
        float mu0 = e0 / s, mu1 = e1 / s;
        out[OUT_MU + b * 2]     = mu0;
        out[OUT_MU + b * 2 + 1] = mu1;
        float ss = 0.f;
        for (int j = 0; j < 80; j++) ss += wv[j] * wv[j];
        float wn = fmaxf(sqrtf(ss), 1e-12f);
        sc[2] = 3.16227766017f * sqrtf(mu0) / wn;
    }
    __syncthreads();
    if (t < 80) out[b * 80 + t] = wv[t] * sc[2];
}

extern "C" void kernel_launch(void* const* d_in, const int* in_sizes, int n_in,
                              void* d_out, int out_size, void* d_ws, size_t ws_size,
                              hipStream_t stream) {
    const float* x    = (const float*)d_in[0];
    const float* Hre  = (const float*)d_in[1];
    const float* Him  = (const float*)d_in[2];
    const float* chre = (const float*)d_in[3];
    const float* chim = (const float*)d_in[4];
    const float* c1w  = (const float*)d_in[5];
    const float* c1b  = (const float*)d_in[6];
    const float* c2w  = (const float*)d_in[7];
    const float* c2b  = (const float*)d_in[8];
    const float* pl1w = (const float*)d_in[9];
    const float* pl1b = (const float*)d_in[10];
    const float* pl2w = (const float*)d_in[11];
    const float* pl2b = (const float*)d_in[12];
    const float* b1w  = (const float*)d_in[13];
    const float* b1b  = (const float*)d_in[14];
    const float* b2w  = (const float*)d_in[15];
    const float* b2b  = (const float*)d_in[16];
    const float* b3w  = (const float*)d_in[17];
    const float* b3b  = (const float*)d_in[18];
    const float* p1w  = (const float*)d_in[19];
    const float* p1b  = (const float*)d_in[20];
    const float* p2w  = (const float*)d_in[21];
    const float* p2b  = (const float*)d_in[22];
    float* out = (float*)d_out;

    char* ws = (char*)d_ws;
    unsigned short* Ah = (unsigned short*)(ws + 0);           //  68,157,440 B
    unsigned short* Al = (unsigned short*)(ws + 68157440u);   //  68,157,440 B
    float* P           = (float*)(ws + 136314880u);           //  33,554,432 B  (end 169,869,312)
    unsigned short* Bh = (unsigned short*)(ws + 169869312u);  //  17,039,360 B
    unsigned short* Bl = (unsigned short*)(ws + 186908672u);  //  17,039,360 B  (end 203,948,032; ws >= this, proven R7)
    // w2 fragment stash: last 16 KB of P (inside slice 15). Written by k_cvtW first;
    // read by k_conv z0/z1; slice 15 is only (re)written by k_gemm z1 sk=7, which is
    // stream-ordered AFTER the last k_conv -> safe.
    unsigned short* Wq = (unsigned short*)(ws + 169869312u - 16384u);

    k_cvtW<<<1, 256, 0, stream>>>(c2w, Wq);
    k_cvtB<<<8320, 256, 0, stream>>>((const float4*)pl1w, (ushort4*)Bh, (ushort4*)Bl, 2129920);
    for (int z = 0; z < 2; z++) {
        k_conv<<<dim3(2048, 9), 256, 0, stream>>>(x, c1w, c1b, Wq, c2b, Ah, Al, z);
        k_gemm<<<dim3(32, 2, 8), 256, 0, stream>>>(Ah, Al, Bh, Bl, P, z);
    }
    k_head<<<2048, 128, 0, stream>>>(P, pl1b, pl2w, pl2b, out);
    k_tail<<<512, 256, 0, stream>>>(Hre, Him, chre, chim, b1w, b1b, b2w, b2b,
                                    b3w, b3b, p1w, p1b, p2w, p2b, out);
}